// Round 11
// baseline (92.269 us; speedup 1.0000x reference)
//
#include <hip/hip_runtime.h>
#include <hip/hip_bf16.h>

#define N_TAGS 128
#define T_LEN  256
#define BSZ    256
#define ROOT_T 126
#define END_T  127

typedef _Float16 h2 __attribute__((ext_vector_type(2)));
typedef _Float16 h4 __attribute__((ext_vector_type(4)));
typedef float f32x4 __attribute__((ext_vector_type(4)));
typedef int   i32x4 __attribute__((ext_vector_type(4)));

static __device__ __forceinline__ h2 pkrtz(float a, float b) {
  return __builtin_bit_cast(h2, __builtin_amdgcn_cvt_pkrtz(a, b));
}
static __device__ __forceinline__ float rfl(float x) {
  return __int_as_float(__builtin_amdgcn_readfirstlane(__float_as_int(x)));
}
// Pull lane k's packed h2 to a wave-uniform (SGPR) value. k is a literal.
static __device__ __forceinline__ h2 rdl(h2 v, int k) {
  return __builtin_bit_cast(h2, __builtin_amdgcn_readlane(__builtin_bit_cast(int, v), k));
}
static __device__ __forceinline__ float fdot2(h2 a, h2 b, float c) {
#if __has_builtin(__builtin_amdgcn_fdot2)
  return __builtin_amdgcn_fdot2(a, b, c, false);
#else
  float d;
  asm("v_dot2_f32_f16 %0, %1, %2, %3" : "=v"(d) : "v"(a), "v"(b), "v"(c));
  return d;
#endif
}
static __device__ __forceinline__ float wave_max(float x) {
  #pragma unroll
  for (int d = 1; d < 64; d <<= 1) x = fmaxf(x, __shfl_xor(x, d));
  return x;
}

// LDS-free 128-length dual dot (readlane broadcast -> SGPR operand of fdot2).
static __device__ __forceinline__ void dotRL(h2 vp,
                                             const h2 (&EA)[64], const h2 (&EB)[64],
                                             float& s0, float& s1) {
  float a0=0.f,a1=0.f,a2=0.f,a3=0.f, b0=0.f,b1=0.f,b2=0.f,b3=0.f;
  #pragma unroll
  for (int q = 0; q < 64; q += 4) {
    const h2 u0 = rdl(vp, q + 0);
    const h2 u1 = rdl(vp, q + 1);
    const h2 u2 = rdl(vp, q + 2);
    const h2 u3 = rdl(vp, q + 3);
    a0 = fdot2(u0, EA[q + 0], a0);  b0 = fdot2(u0, EB[q + 0], b0);
    a1 = fdot2(u1, EA[q + 1], a1);  b1 = fdot2(u1, EB[q + 1], b1);
    a2 = fdot2(u2, EA[q + 2], a2);  b2 = fdot2(u2, EB[q + 2], b2);
    a3 = fdot2(u3, EA[q + 3], a3);  b3 = fdot2(u3, EB[q + 3], b3);
  }
  s0 = (a0 + a1) + (a2 + a3);
  s1 = (b0 + b1) + (b2 + b3);
}

// One block per batch, 128 threads = 2 waves.
// NEW vs round 10: ALL feat rows used inside the loops (rows 1..254) are
// preloaded to LDS as packed f16 in the prologue. The main loop has ZERO
// global loads; its only memory op is one ds_read_b32 prefetched 2 steps
// ahead (in-order DS, ~120cy << step time). Rows 0 and 255 are consumed from
// global in the inits. bb/sred alias feat rows 251-254, which are only read
// by wave 1 at k=0..3 (same-wave ordering => safe).
__global__ void
__attribute__((amdgpu_flat_work_group_size(128, 128), amdgpu_waves_per_eu(1, 1)))
crf_fwd_kernel(
    const float* __restrict__ feats,   // [BSZ][T_LEN][N_TAGS]
    const int*   __restrict__ tags,    // [BSZ][T_LEN]
    const int*   __restrict__ mask,    // [BSZ][T_LEN]
    const float* __restrict__ lt,      // [N_TAGS][N_TAGS]
    float*       __restrict__ per_batch)
{
  const int b    = blockIdx.x;
  const int tid  = threadIdx.x;
  const int lane = tid & 63;
  const int wave = tid >> 6;

  // 64KB arena: E-build stage (16.5KB) -> feat rows 1..254 as h2 (65024B).
  __shared__ __align__(16) char smem[65536];
  float* stage = (float*)smem;
  #define FROW(r) ((h2*)smem + (size_t)((r) - 1) * 64)
  float* bb   = (float*)(smem + 64000);   // aliases feat rows 251-254
  float* sred = (float*)(smem + 64520);

  const float* fb = feats + (size_t)b * T_LEN * N_TAGS;
  const int*   tb = tags  + b * T_LEN;

  // ---- sequence length (prefix mask), per-wave independent ----
  int len;
  {
    const i32x4 mv = ((const i32x4*)(mask + b * T_LEN))[lane];
    int v = mv.x + mv.y + mv.z + mv.w;
    #pragma unroll
    for (int d = 1; d < 64; d <<= 1) v += __shfl_xor(v, d);
    len = __builtin_amdgcn_readfirstlane(v);
  }

  // ---- build f16 register-resident E = exp(lt) ----
  h2 EA[64], EB[64];
  #pragma unroll
  for (int c = 0; c < 4; ++c) {
    __syncthreads();
    #pragma unroll
    for (int rr = 0; rr < 32; ++rr)
      stage[rr * 129 + tid] = __expf(lt[(c * 32 + rr) * N_TAGS + tid]);
    __syncthreads();
    if (wave == 0) {
      #pragma unroll
      for (int k = 0; k < 16; ++k) {
        h2 ea, eb;
        ea.x = (_Float16)stage[(2*k)   * 129 + 2*lane];
        ea.y = (_Float16)stage[(2*k+1) * 129 + 2*lane];
        eb.x = (_Float16)stage[(2*k)   * 129 + 2*lane + 1];
        eb.y = (_Float16)stage[(2*k+1) * 129 + 2*lane + 1];
        EA[c*16 + k] = ea;
        EB[c*16 + k] = eb;
      }
    } else if ((lane >> 4) == c) {        // rows 2l,2l+1 live in chunk c
      const int r0 = 2 * lane - 32 * c;
      #pragma unroll
      for (int q = 0; q < 64; ++q) {
        h2 ea, eb;
        ea.x = (_Float16)stage[r0       * 129 + 2*q];
        ea.y = (_Float16)stage[r0       * 129 + 2*q + 1];
        eb.x = (_Float16)stage[(r0 + 1) * 129 + 2*q];
        eb.y = (_Float16)stage[(r0 + 1) * 129 + 2*q + 1];
        EA[q] = ea;
        EB[q] = eb;
      }
    }
  }
  __syncthreads();                        // stage reads done; reuse as feat LDS

  // ---- preload feat rows 1..254 into LDS as packed h2 (coalesced) ----
  {
    const int j = tid & 31;               // f32x4 index within row
    #pragma unroll 8
    for (int it = 0; it < 64; ++it) {
      const int r = it * 4 + (tid >> 5);  // 0..255
      if (r >= 1 && r <= 254) {
        const f32x4 v = ((const f32x4*)(fb + (size_t)r * N_TAGS))[j];
        const h2 lo = pkrtz(v.x, v.y);
        const h2 hi = pkrtz(v.z, v.w);
        ((h4*)FROW(r))[j] = __builtin_shufflevector(lo, hi, 0, 1, 2, 3);
      }
    }
  }
  __syncthreads();

  float st0, st1;

  if (wave == 0) {
    // ========== FORWARD: alpha, steps t=1..128 (active iff t<len) ==========
    {
      const float2 f0 = ((const float2*)fb)[lane];           // row 0 (global)
      st0 = lt[ROOT_T * N_TAGS + 2*lane]     + f0.x;
      st1 = lt[ROOT_T * N_TAGS + 2*lane + 1] + f0.y;
    }
    h2 gb[2];
    gb[1] = FROW(1)[lane];                // row 1 (used t=1)
    gb[0] = FROW(2)[lane];                // row 2 (used t=2)
    float m_cur = rfl(st0) + 2.0f;
    h2 vp = pkrtz(__expf(st0 - m_cur), __expf(st1 - m_cur));

    #pragma unroll 2
    for (int t = 1; t <= 128; ++t) {
      float s0, s1;
      dotRL(vp, EA, EB, s0, s1);
      const h2 fa = gb[t & 1];                               // row t
      const int pr = (t + 2 <= 128) ? (t + 2) : 128;
      gb[t & 1] = FROW(pr)[lane];                            // row t+2
      const float nf0 = m_cur + __logf(s0) + (float)fa.x;
      const float nf1 = m_cur + __logf(s1) + (float)fa.y;
      const bool act = (t < len);
      st0 = act ? nf0 : st0;  st1 = act ? nf1 : st1;
      const float m = rfl(st0) + 2.0f;
      vp = pkrtz(__expf(st0 - m), __expf(st1 - m));
      m_cur = m;
    }
    // st = alpha_128
  } else {
    // ========== BACKWARD: beta, step k uses f[254-k] at the write;
    //            active iff 256-len <= k <= 126; ends at beta_128 ==========
    st0 = lt[(2*lane)     * N_TAGS + END_T];   // beta_{len-1}
    st1 = lt[(2*lane + 1) * N_TAGS + END_T];
    const float2 fw = ((const float2*)(fb + 255 * N_TAGS))[lane];  // row 255 (global)
    h2 gb[2];
    gb[0] = FROW(254)[lane];              // row 254 (used k=0)
    gb[1] = FROW(253)[lane];              // row 253 (used k=1)
    const float y0i = st0 + fw.x, y1i = st1 + fw.y;
    float m_cur = rfl(y0i) + 2.0f;
    h2 vp = pkrtz(__expf(y0i - m_cur), __expf(y1i - m_cur));

    const int kmin = 256 - len;              // first active step
    #pragma unroll 2
    for (int k = 0; k <= 127; ++k) {
      float s0, s1;
      dotRL(vp, EA, EB, s0, s1);
      const float nb0 = m_cur + __logf(s0);
      const float nb1 = m_cur + __logf(s1);
      const bool act = (k >= kmin) && (k <= 126);
      st0 = act ? nb0 : st0;  st1 = act ? nb1 : st1;
      const h2 fa = gb[k & 1];                               // row 254-k
      const int pr = (252 - k >= 127) ? (252 - k) : 127;
      gb[k & 1] = FROW(pr)[lane];                            // row 252-k
      const float y0 = st0 + (float)fa.x, y1 = st1 + (float)fa.y;
      const float m = rfl(y0) + 2.0f;
      vp = pkrtz(__expf(y0 - m), __expf(y1 - m));
      m_cur = m;
    }
    // st = beta_128 (feat LDS dead from here; bb aliases rows 251-254)
    bb[2*lane]     = st0;
    bb[2*lane + 1] = st1;
  }
  __syncthreads();

  // ---- gold-path score: 2 timesteps per thread (global f32 feats) ----
  float c = 0.f;
  #pragma unroll
  for (int q = 0; q < 2; ++q) {
    const int t  = tid + q * N_TAGS;
    const int tg = tb[t];
    if (t == 0)                           c += lt[ROOT_T * N_TAGS + tg];
    if (t >= 1 && t < len)                c += lt[tb[t - 1] * N_TAGS + tg];
    if (t < len && t <= T_LEN - 2)        c += fb[t * N_TAGS + tg];
    if (t == len - 1)                     c += lt[tg * N_TAGS + END_T];
    if (t == T_LEN - 1 && len == T_LEN)   c += fb[t * N_TAGS + tg];
  }
  #pragma unroll
  for (int d = 1; d < 64; d <<= 1) c += __shfl_xor(c, d);
  if (lane == 0) sred[wave] = c;

  // ---- partition: logsumexp(alpha_128 + beta_128), wave 0 ----
  float part = 0.f;
  if (wave == 0) {
    const float x0 = st0 + bb[2*lane];
    const float x1 = st1 + bb[2*lane + 1];
    const float mw = wave_max(fmaxf(x0, x1));
    float e = __expf(x0 - mw) + __expf(x1 - mw);
    #pragma unroll
    for (int d = 1; d < 64; d <<= 1) e += __shfl_xor(e, d);
    part = mw + __logf(e);
  }
  __syncthreads();

  if (tid == 0) per_batch[b] = part - (sred[0] + sred[1]);
}

// Deterministic final reduction: mean over 256 per-batch values.
__global__ __launch_bounds__(256) void crf_reduce_kernel(
    const float* __restrict__ per_batch, float* __restrict__ out)
{
  const int tid = threadIdx.x;
  float v = per_batch[tid] * (1.0f / BSZ);
  #pragma unroll
  for (int d = 1; d < 64; d <<= 1) v += __shfl_xor(v, d);
  __shared__ float r[4];
  if ((tid & 63) == 0) r[tid >> 6] = v;
  __syncthreads();
  if (tid == 0) out[0] = r[0] + r[1] + r[2] + r[3];
}

extern "C" void kernel_launch(void* const* d_in, const int* in_sizes, int n_in,
                              void* d_out, int out_size, void* d_ws, size_t ws_size,
                              hipStream_t stream) {
  (void)in_sizes; (void)n_in; (void)out_size; (void)ws_size;
  const float* feats = (const float*)d_in[0];
  const int*   tags  = (const int*)d_in[1];
  const int*   mask  = (const int*)d_in[2];
  const float* lt    = (const float*)d_in[3];
  float* per_batch = (float*)d_ws;   // 256 floats of scratch

  crf_fwd_kernel<<<BSZ, 128, 0, stream>>>(feats, tags, mask, lt, per_batch);
  crf_reduce_kernel<<<1, 256, 0, stream>>>(per_batch, (float*)d_out);
}

// Round 13
// 79.989 us; speedup vs baseline: 1.1535x; 1.1535x over previous
//
#include <hip/hip_runtime.h>
#include <hip/hip_bf16.h>

#define N_TAGS 128
#define T_LEN  256
#define BSZ    256
#define ROOT_T 126
#define END_T  127

typedef _Float16 h2 __attribute__((ext_vector_type(2)));
typedef int   i32x4 __attribute__((ext_vector_type(4)));

static __device__ __forceinline__ h2 pkrtz(float a, float b) {
  return __builtin_bit_cast(h2, __builtin_amdgcn_cvt_pkrtz(a, b));
}
static __device__ __forceinline__ float rfl(float x) {
  return __int_as_float(__builtin_amdgcn_readfirstlane(__float_as_int(x)));
}
// Pull lane k's packed h2 to a wave-uniform (SGPR) value. k is a literal.
static __device__ __forceinline__ h2 rdl(h2 v, int k) {
  return __builtin_bit_cast(h2, __builtin_amdgcn_readlane(__builtin_bit_cast(int, v), k));
}
static __device__ __forceinline__ float fdot2(h2 a, h2 b, float c) {
#if __has_builtin(__builtin_amdgcn_fdot2)
  return __builtin_amdgcn_fdot2(a, b, c, false);
#else
  float d;
  asm("v_dot2_f32_f16 %0, %1, %2, %3" : "=v"(d) : "v"(a), "v"(b), "v"(c));
  return d;
#endif
}
static __device__ __forceinline__ float wave_max(float x) {
  #pragma unroll
  for (int d = 1; d < 64; d <<= 1) x = fmaxf(x, __shfl_xor(x, d));
  return x;
}

// LDS-free 128-length dual dot (readlane broadcast -> SGPR operand of fdot2).
static __device__ __forceinline__ void dotRL(h2 vp,
                                             const h2 (&EA)[64], const h2 (&EB)[64],
                                             float& s0, float& s1) {
  float a0=0.f,a1=0.f,a2=0.f,a3=0.f, b0=0.f,b1=0.f,b2=0.f,b3=0.f;
  #pragma unroll
  for (int q = 0; q < 64; q += 4) {
    const h2 u0 = rdl(vp, q + 0);
    const h2 u1 = rdl(vp, q + 1);
    const h2 u2 = rdl(vp, q + 2);
    const h2 u3 = rdl(vp, q + 3);
    a0 = fdot2(u0, EA[q + 0], a0);  b0 = fdot2(u0, EB[q + 0], b0);
    a1 = fdot2(u1, EA[q + 1], a1);  b1 = fdot2(u1, EB[q + 1], b1);
    a2 = fdot2(u2, EA[q + 2], a2);  b2 = fdot2(u2, EB[q + 2], b2);
    a3 = fdot2(u3, EA[q + 3], a3);  b3 = fdot2(u3, EB[q + 3], b3);
  }
  s0 = (a0 + a1) + (a2 + a3);
  s1 = (b0 + b1) + (b2 + b3);
}

// One block per batch, 128 threads = 2 waves, zero LDS/barriers in main loops.
// Wave 0 (fwd): lane l owns columns 2l,2l+1 of E=exp(lt) as f16 row-pairs.
// Wave 1 (bwd): lane l owns rows    2l,2l+1 of E as f16 col-pairs.
// SINGLE change vs round 10: __launch_bounds__(128,1) instead of the
// amdgpu_waves_per_eu attribute. Round 4 evidence: this form unlocked the
// full 256-VGPR budget (VGPR_Count=256) while the attr form capped at 132,
// forcing EA/EB into AGPRs with per-use v_accvgpr_read shuttles.
__global__ __launch_bounds__(128, 1) void crf_fwd_kernel(
    const float* __restrict__ feats,   // [BSZ][T_LEN][N_TAGS]
    const int*   __restrict__ tags,    // [BSZ][T_LEN]
    const int*   __restrict__ mask,    // [BSZ][T_LEN]
    const float* __restrict__ lt,      // [N_TAGS][N_TAGS]
    float*       __restrict__ per_batch)
{
  const int b    = blockIdx.x;
  const int tid  = threadIdx.x;
  const int lane = tid & 63;
  const int wave = tid >> 6;

  __shared__ float stage[32 * 129];
  __shared__ float bb[N_TAGS];
  __shared__ float sred[2];

  const float* fb = feats + (size_t)b * T_LEN * N_TAGS;
  const int*   tb = tags  + b * T_LEN;

  // ---- sequence length (prefix mask), per-wave independent ----
  int len;
  {
    const i32x4 mv = ((const i32x4*)(mask + b * T_LEN))[lane];
    int v = mv.x + mv.y + mv.z + mv.w;
    #pragma unroll
    for (int d = 1; d < 64; d <<= 1) v += __shfl_xor(v, d);
    len = __builtin_amdgcn_readfirstlane(v);
  }

  // ---- build f16 register-resident E = exp(lt) ----
  // fwd lane l: EA[q]={E[2q][2l],E[2q+1][2l]}, EB same for col 2l+1.
  // bwd lane l: EA[q]={E[2l][2q],E[2l][2q+1]}, EB same for row 2l+1.
  h2 EA[64], EB[64];
  #pragma unroll
  for (int c = 0; c < 4; ++c) {
    __syncthreads();
    #pragma unroll
    for (int rr = 0; rr < 32; ++rr)
      stage[rr * 129 + tid] = __expf(lt[(c * 32 + rr) * N_TAGS + tid]);
    __syncthreads();
    if (wave == 0) {
      #pragma unroll
      for (int k = 0; k < 16; ++k) {
        h2 ea, eb;
        ea.x = (_Float16)stage[(2*k)   * 129 + 2*lane];
        ea.y = (_Float16)stage[(2*k+1) * 129 + 2*lane];
        eb.x = (_Float16)stage[(2*k)   * 129 + 2*lane + 1];
        eb.y = (_Float16)stage[(2*k+1) * 129 + 2*lane + 1];
        EA[c*16 + k] = ea;
        EB[c*16 + k] = eb;
      }
    } else if ((lane >> 4) == c) {        // rows 2l,2l+1 live in chunk c
      const int r0 = 2 * lane - 32 * c;
      #pragma unroll
      for (int q = 0; q < 64; ++q) {
        h2 ea, eb;
        ea.x = (_Float16)stage[r0       * 129 + 2*q];
        ea.y = (_Float16)stage[r0       * 129 + 2*q + 1];
        eb.x = (_Float16)stage[(r0 + 1) * 129 + 2*q];
        eb.y = (_Float16)stage[(r0 + 1) * 129 + 2*q + 1];
        EA[q] = ea;
        EB[q] = eb;
      }
    }
  }

  float st0, st1;

  if (wave == 0) {
    // ========== FORWARD: alpha, steps t=1..128 (active iff t<len) ==========
    {
      const float2 f0 = ((const float2*)fb)[lane];
      st0 = lt[ROOT_T * N_TAGS + 2*lane]     + f0.x;
      st1 = lt[ROOT_T * N_TAGS + 2*lane + 1] + f0.y;
    }
    // depth-4 rotating prefetch buffer: buf[t&3] holds feat row t
    float2 buf[4];
    buf[1] = ((const float2*)(fb + 1 * N_TAGS))[lane];
    buf[2] = ((const float2*)(fb + 2 * N_TAGS))[lane];
    buf[3] = ((const float2*)(fb + 3 * N_TAGS))[lane];
    buf[0] = ((const float2*)(fb + 4 * N_TAGS))[lane];
    float m_cur = rfl(st0) + 2.0f;
    h2 vp = pkrtz(__expf(st0 - m_cur), __expf(st1 - m_cur));

    #pragma unroll 4
    for (int t = 1; t <= 128; ++t) {
      float s0, s1;
      dotRL(vp, EA, EB, s0, s1);
      const float2 fa = buf[t & 3];                           // row t
      buf[t & 3] = ((const float2*)(fb + (t + 4) * N_TAGS))[lane];  // row t+4
      const float nf0 = m_cur + __logf(s0) + fa.x;
      const float nf1 = m_cur + __logf(s1) + fa.y;
      const bool act = (t < len);
      st0 = act ? nf0 : st0;  st1 = act ? nf1 : st1;
      const float m = rfl(st0) + 2.0f;
      vp = pkrtz(__expf(st0 - m), __expf(st1 - m));
      m_cur = m;
    }
    // st = alpha_128 (frozen at alpha_{len-1} for len<=128)
  } else {
    // ========== BACKWARD: beta, step k uses f[255-k] read / f[254-k] write;
    //            active iff 256-len <= k <= 126; ends at beta_128 ==========
    st0 = lt[(2*lane)     * N_TAGS + END_T];   // beta_{len-1}
    st1 = lt[(2*lane + 1) * N_TAGS + END_T];
    const float2 fw = ((const float2*)(fb + 255 * N_TAGS))[lane];  // f255
    // depth-4 rotating prefetch buffer: buf[k&3] holds feat row 254-k
    float2 buf[4];
    buf[0] = ((const float2*)(fb + 254 * N_TAGS))[lane];
    buf[1] = ((const float2*)(fb + 253 * N_TAGS))[lane];
    buf[2] = ((const float2*)(fb + 252 * N_TAGS))[lane];
    buf[3] = ((const float2*)(fb + 251 * N_TAGS))[lane];
    const float y0i = st0 + fw.x, y1i = st1 + fw.y;
    float m_cur = rfl(y0i) + 2.0f;
    h2 vp = pkrtz(__expf(y0i - m_cur), __expf(y1i - m_cur));

    const int kmin = 256 - len;              // first active step
    #pragma unroll 4
    for (int k = 0; k <= 127; ++k) {
      float s0, s1;
      dotRL(vp, EA, EB, s0, s1);
      const float nb0 = m_cur + __logf(s0);
      const float nb1 = m_cur + __logf(s1);
      const bool act = (k >= kmin) && (k <= 126);
      st0 = act ? nb0 : st0;  st1 = act ? nb1 : st1;
      const float2 fa = buf[k & 3];                           // row 254-k
      buf[k & 3] = ((const float2*)(fb + (250 - k) * N_TAGS))[lane]; // row 250-k
      const float y0 = st0 + fa.x, y1 = st1 + fa.y;
      const float m = rfl(y0) + 2.0f;
      vp = pkrtz(__expf(y0 - m), __expf(y1 - m));
      m_cur = m;
    }
    // st = beta_128
    bb[2*lane]     = st0;
    bb[2*lane + 1] = st1;
  }
  __syncthreads();

  // ---- gold-path score: 2 timesteps per thread ----
  float c = 0.f;
  #pragma unroll
  for (int q = 0; q < 2; ++q) {
    const int t  = tid + q * N_TAGS;
    const int tg = tb[t];
    if (t == 0)                           c += lt[ROOT_T * N_TAGS + tg];
    if (t >= 1 && t < len)                c += lt[tb[t - 1] * N_TAGS + tg];
    if (t < len && t <= T_LEN - 2)        c += fb[t * N_TAGS + tg];
    if (t == len - 1)                     c += lt[tg * N_TAGS + END_T];
    if (t == T_LEN - 1 && len == T_LEN)   c += fb[t * N_TAGS + tg];
  }
  #pragma unroll
  for (int d = 1; d < 64; d <<= 1) c += __shfl_xor(c, d);
  if (lane == 0) sred[wave] = c;

  // ---- partition: logsumexp(alpha_128 + beta_128), wave 0 ----
  float part = 0.f;
  if (wave == 0) {
    const float x0 = st0 + bb[2*lane];
    const float x1 = st1 + bb[2*lane + 1];
    const float mw = wave_max(fmaxf(x0, x1));
    float e = __expf(x0 - mw) + __expf(x1 - mw);
    #pragma unroll
    for (int d = 1; d < 64; d <<= 1) e += __shfl_xor(e, d);
    part = mw + __logf(e);
  }
  __syncthreads();

  if (tid == 0) per_batch[b] = part - (sred[0] + sred[1]);
}

// Deterministic final reduction: mean over 256 per-batch values.
__global__ __launch_bounds__(256) void crf_reduce_kernel(
    const float* __restrict__ per_batch, float* __restrict__ out)
{
  const int tid = threadIdx.x;
  float v = per_batch[tid] * (1.0f / BSZ);
  #pragma unroll
  for (int d = 1; d < 64; d <<= 1) v += __shfl_xor(v, d);
  __shared__ float r[4];
  if ((tid & 63) == 0) r[tid >> 6] = v;
  __syncthreads();
  if (tid == 0) out[0] = r[0] + r[1] + r[2] + r[3];
}

extern "C" void kernel_launch(void* const* d_in, const int* in_sizes, int n_in,
                              void* d_out, int out_size, void* d_ws, size_t ws_size,
                              hipStream_t stream) {
  (void)in_sizes; (void)n_in; (void)out_size; (void)ws_size;
  const float* feats = (const float*)d_in[0];
  const int*   tags  = (const int*)d_in[1];
  const int*   mask  = (const int*)d_in[2];
  const float* lt    = (const float*)d_in[3];
  float* per_batch = (float*)d_ws;   // 256 floats of scratch

  crf_fwd_kernel<<<BSZ, 128, 0, stream>>>(feats, tags, mask, lt, per_batch);
  crf_reduce_kernel<<<1, 256, 0, stream>>>(per_batch, (float*)d_out);
}